// Round 10
// baseline (256.859 us; speedup 1.0000x reference)
//
#include <hip/hip_runtime.h>
#include <math.h>

// 4 threads/ray, REGISTER-ARRAY-FREE redo of R6 (math validated there: absmax 0.0039;
// perf failed only via reg-array spill, 180 MB scratch). All indexed state in two LDS
// arrays; scalars + width-4 DPP shuffles otherwise.
//  - streams/SIMD: 64 rays/block x 33.3 KB LDS -> 4 blocks/CU -> 16 waves/CU = 4/SIMD
//    (R4/R7/R8 proved busy ~94k cyc/SIMD is invariant; only stream count was stuck at 2).
//  - cdf built in-place: raw local cumsum written in P1-loop1, rescaled in P1-loop2.
//  - P2: zero sigmoids (cdf from P1 weights); 17 independent 6-probe binary searches.
//  - P3: merge-rank decomposition (R3/R6-validated): PA via cdf identity, PB-incl
//    overwrites cdf after last read (+16 op-only sigmoid recomputes), jB by search.
//  - per-ray LDS columns touched only by the ray's own 4 lanes (same wave) -> no
//    __syncthreads; __threadfence_block() (lgkmcnt drain) at phase boundaries.
//  - R9 lessons reverted: native v_rcp_f32 (short latency), scalar fp32, split norm
//    kernel (counter-spin barrier measured ~+40 us twice -> abandoned).

#define NT 256
#define SEG 16
#define PTS 64
#define NRAYS (2*256*256)
#define NEARV 0.1f
#define STEPV (1.9f/63.0f)
#define INVSTEP (1.0f/(1.9f/63.0f))
#define NL2E (-1.4426950408889634f)
#define LSTR 65                      // [point][64 rays + 1 pad]; 65%32==1 -> bank=(p+ray)%32

extern "C" __device__ float __ocml_native_exp2_f32(float);

__device__ __forceinline__ float sig_pm(float arg) {   // arg is already -x*log2e
    return __builtin_amdgcn_rcpf(1.0f + __ocml_native_exp2_f32(arg));
}

__global__ __launch_bounds__(NT) void nerf_main(
    const float* __restrict__ tm, const float* __restrict__ wq,
    float* __restrict__ out, unsigned int* __restrict__ mmx)
{
    __shared__ float cdf_[PTS * LSTR];   // raw cum -> cdf -> (P3) PB-inclusive
    __shared__ float fde_[PTS * LSTR];   // fine depths (sorted)

    const int tid = threadIdx.x;
    const int t   = tid & 3;             // segment slot within ray
    const int ray = tid >> 2;            // ray within block (0..63); ray's 4 lanes same wave
    const int r   = blockIdx.x * 64 + ray;
    const int b   = r >> 16;
    const int n   = r & 65535;
    const int ii  = n >> 8;
    const int jj  = n & 255;

    const float cx = (1.0f + (float)jj * (-2.0f/255.0f)) * (1.0f/4.2f);
    const float cy = (1.0f + (float)ii * (-2.0f/255.0f)) * (1.0f/4.2f);

    const float* tmb = tm + b*12;
    const float dx = tmb[0]*cx + tmb[1]*cy + tmb[2];
    const float dy = tmb[4]*cx + tmb[5]*cy + tmb[6];
    const float dz = tmb[8]*cx + tmb[9]*cy + tmb[10];
    const float ox = tmb[3], oy = tmb[7], oz = tmb[11];

    float bA0, bA1, bA2, bA3, sA0, sA1, sA2, sA3;      // feat[c]*(-log2e) = bA + d*sA
    {
        float s0_ = dx*wq[0] + dy*wq[4] + dz*wq[8];
        float s1_ = dx*wq[1] + dy*wq[5] + dz*wq[9];
        float s2_ = dx*wq[2] + dy*wq[6] + dz*wq[10];
        float s3_ = dx*wq[3] + dy*wq[7] + dz*wq[11];
        float b0_ = ox*wq[0] + oy*wq[4] + oz*wq[8]  + dx*wq[12] + dy*wq[16] + dz*wq[20];
        float b1_ = ox*wq[1] + oy*wq[5] + oz*wq[9]  + dx*wq[13] + dy*wq[17] + dz*wq[21];
        float b2_ = ox*wq[2] + oy*wq[6] + oz*wq[10] + dx*wq[14] + dy*wq[18] + dz*wq[22];
        float b3_ = ox*wq[3] + oy*wq[7] + oz*wq[11] + dx*wq[15] + dy*wq[19] + dz*wq[23];
        sA0 = s0_*NL2E; sA1 = s1_*NL2E; sA2 = s2_*NL2E; sA3 = s3_*NL2E;
        bA0 = b0_*NL2E; bA1 = b1_*NL2E; bA2 = b2_*NL2E; bA3 = b3_*NL2E;
    }

    // ============ P1 loop1: coarse segment [16t,16t+16), raw cumsum to LDS ============
    float T = 1.0f, cacc = 0.0f, sv0 = 0.0f, sv1 = 0.0f, sv2 = 0.0f;
    #pragma unroll 4
    for (int i = 0; i < SEG; i++) {
        int p = SEG*t + i;
        float d  = fmaf((float)p, STEPV, NEARV);
        float op = sig_pm(bA0 + d*sA0);
        float v0 = sig_pm(bA1 + d*sA1);
        float v1 = sig_pm(bA2 + d*sA2);
        float v2 = sig_pm(bA3 + d*sA3);
        float w  = op * T;
        cacc += w;
        cdf_[p*LSTR + ray] = cacc;       // raw local cumulative (rescaled in loop2)
        sv0 = fmaf(w, v0, sv0);
        sv1 = fmaf(w, v1, sv1);
        sv2 = fmaf(w, v2, sv2);
        T *= (1.0f - op);
    }
    // width-4 scans (2 DPP shuffle steps), as validated in R6
    float Ti = T;
    { float o = __shfl_up(Ti, 1, 64); if (t >= 1) Ti *= o;
      o = __shfl_up(Ti, 2, 64); if (t >= 2) Ti *= o; }
    float exA; { float o = __shfl_up(Ti, 1, 64); exA = (t == 0) ? 1.0f : o; }

    float segwt = fmaf(exA, cacc, (float)SEG * 1e-5f);
    float S = segwt;
    S += __shfl_xor(S, 1, 64); S += __shfl_xor(S, 2, 64);
    float Wi = segwt;
    { float o = __shfl_up(Wi, 1, 64); if (t >= 1) Wi += o;
      o = __shfl_up(Wi, 2, 64); if (t >= 2) Wi += o; }
    float Wexc; { float o = __shfl_up(Wi, 1, 64); Wexc = (t == 0) ? 0.0f : o; }
    const float Sinv = __builtin_amdgcn_rcpf(S);

    float a0 = exA*sv0, a1 = exA*sv1, a2 = exA*sv2;
    a0 += __shfl_xor(a0, 1, 64); a0 += __shfl_xor(a0, 2, 64);
    a1 += __shfl_xor(a1, 1, 64); a1 += __shfl_xor(a1, 2, 64);
    a2 += __shfl_xor(a2, 1, 64); a2 += __shfl_xor(a2, 2, 64);
    if (t == 0) {
        out[(b*3+0)*65536 + n] = a0;
        out[(b*3+1)*65536 + n] = a1;
        out[(b*3+2)*65536 + n] = a2;
    }

    // ============ P1 loop2: rescale raw cum -> cdf (R6 formula) ============
    #pragma unroll 4
    for (int i = 0; i < SEG; i++) {
        int a = (SEG*t + i)*LSTR + ray;
        float c = cdf_[a];
        cdf_[a] = (Wexc + fmaf(exA, c, (float)(i+1) * 1e-5f)) * Sinv;
    }
    __threadfence_block();               // order in-wave LDS writes before cross-lane reads

    // ============ P2: 17 bins, independent 6-probe searches; zero sigmoids ============
    const float c63 = cdf_[63*LSTR + ray];
    float bin_prev = 0.0f;
    #pragma unroll 1
    for (int m = 0; m <= SEG; m++) {
        float u = (float)(SEG*t + m) * 0.015625f;      // exact k/64
        int lo = 0;
        #pragma unroll
        for (int s = 32; s >= 1; s >>= 1) {            // searchsorted 'right', idx<=62
            float cc = cdf_[(lo + s - 1)*LSTR + ray];
            if (cc <= u) lo += s;
        }
        int ind = (c63 <= u) ? 64 : lo;
        int below = min(max(ind - 1, 0), 63);
        int above = min(ind, 63);
        float c0 = cdf_[below*LSTR + ray];
        float c1 = cdf_[above*LSTR + ray];
        float d0 = fmaf((float)below, STEPV, NEARV);
        float d1 = fmaf((float)above, STEPV, NEARV);
        float den = c1 - c0;
        den = (den < 1e-8f) ? 1.0f : den;              // ref guard
        float tt = (u - c0) * __builtin_amdgcn_rcpf(den);
        tt = fminf(fmaxf(tt, 0.0f), 1.0f);
        float bin = fmaf(tt, d1 - d0, d0);
        if (m > 0) fde_[(SEG*t + m - 1)*LSTR + ray] = 0.5f * (bin_prev + bin);
        bin_prev = bin;
    }
    __threadfence_block();

    // ============ P3a: fine-side (own 16 fine points, re-read from LDS) ============
    float TB = 1.0f, s0 = 0.0f, s1 = 0.0f, s2 = 0.0f, swf = 0.0f, sdf = 0.0f;
    #pragma unroll 4
    for (int i = 0; i < SEG; i++) {
        float dB  = fde_[(SEG*t + i)*LSTR + ray];
        float opB = sig_pm(bA0 + dB*sA0);
        float v0B = sig_pm(bA1 + dB*sA1);
        float v1B = sig_pm(bA2 + dB*sA2);
        float v2B = sig_pm(bA3 + dB*sA3);
        // jA = #{p: d_p <= dB}: closed-form + exact-compare fixup (R6-validated)
        int q0 = (int)floorf((dB - NEARV) * INVSTEP);
        float g0 = fmaf((float)q0,     STEPV, NEARV);
        float g1 = fmaf((float)(q0+1), STEPV, NEARV);
        int jA = q0 + ((g0 <= dB) ? 1 : 0) + ((g1 <= dB) ? 1 : 0);
        float cv = cdf_[max(jA - 1, 0)*LSTR + ray];
        float PAg = 1.0f + (float)jA * 1e-5f - cv * S; // identity: PA=1-(cdf*S - jA*1e-5)
        PAg = (jA == 0) ? 1.0f : PAg;
        float h = opB * TB * PAg;                      // exB applied after scan
        s0 = fmaf(h, v0B, s0);
        s1 = fmaf(h, v1B, s1);
        s2 = fmaf(h, v2B, s2);
        swf += h;
        sdf = fmaf(h, dB, sdf);
        TB *= (1.0f - opB);
    }
    float TBi = TB;
    { float o = __shfl_up(TBi, 1, 64); if (t >= 1) TBi *= o;
      o = __shfl_up(TBi, 2, 64); if (t >= 2) TBi *= o; }
    float exB; { float o = __shfl_up(TBi, 1, 64); exB = (t == 0) ? 1.0f : o; }
    s0 *= exB; s1 *= exB; s2 *= exB; swf *= exB; sdf *= exB;
    __threadfence_block();               // all cdf reads complete before overwrite
    // overwrite cdf with PB-inclusive (op-only recompute; no register arrays)
    float TBr = exB;
    #pragma unroll 4
    for (int i = 0; i < SEG; i++) {
        int a = (SEG*t + i)*LSTR + ray;
        float opB = sig_pm(bA0 + fde_[a]*sA0);
        TBr *= (1.0f - opB);
        cdf_[a] = TBr;
    }
    __threadfence_block();

    // ============ P3b: coarse-side (own 16 coarse points) ============
    const float f63 = fde_[63*LSTR + ray];
    float TA = exA;
    #pragma unroll 4
    for (int i = 0; i < SEG; i++) {
        float d  = fmaf((float)(SEG*t + i), STEPV, NEARV);
        float op = sig_pm(bA0 + d*sA0);
        float v0 = sig_pm(bA1 + d*sA1);
        float v1 = sig_pm(bA2 + d*sA2);
        float v2 = sig_pm(bA3 + d*sA3);
        int lo = 0;
        #pragma unroll
        for (int s = 32; s >= 1; s >>= 1) {            // jB = #{k: fdep_k < d} (strict)
            float ff = fde_[(lo + s - 1)*LSTR + ray];
            if (ff < d) lo += s;
        }
        int jB = (f63 < d) ? 64 : lo;
        float pbv = cdf_[max(jB - 1, 0)*LSTR + ray];
        float PBg = (jB == 0) ? 1.0f : pbv;
        float w2 = op * TA * PBg;
        s0 = fmaf(w2, v0, s0);
        s1 = fmaf(w2, v1, s1);
        s2 = fmaf(w2, v2, s2);
        swf += w2;
        sdf = fmaf(w2, d, sdf);
        TA *= (1.0f - op);
    }
    s0  += __shfl_xor(s0, 1, 64);  s0  += __shfl_xor(s0, 2, 64);
    s1  += __shfl_xor(s1, 1, 64);  s1  += __shfl_xor(s1, 2, 64);
    s2  += __shfl_xor(s2, 1, 64);  s2  += __shfl_xor(s2, 2, 64);
    swf += __shfl_xor(swf, 1, 64); swf += __shfl_xor(swf, 2, 64);
    sdf += __shfl_xor(sdf, 1, 64); sdf += __shfl_xor(sdf, 2, 64);

    float fop  = fminf(fmaxf(swf, 0.0f), 1.0f);
    float rdep = sdf + (1.0f - fop) * 2.0f;            // d_all.max() == 2.0 exactly
    if (t == 0) {
        out[393216 + (b*3+0)*65536 + n] = s0;
        out[393216 + (b*3+1)*65536 + n] = s1;
        out[393216 + (b*3+2)*65536 + n] = s2;
        out[786432 + r] = rdep;
    }

    // min/max via u32 atomicMin on (bits, ~bits); rdep>0 -> u32 order == float order
    unsigned ub  = __float_as_uint(rdep);
    unsigned kmn = (t == 0) ? ub  : 0xFFFFFFFFu;
    unsigned kmx = (t == 0) ? ~ub : 0xFFFFFFFFu;
    #pragma unroll
    for (int m = 32; m >= 1; m >>= 1) {
        unsigned omn = (unsigned)__shfl_xor((int)kmn, m, 64);
        unsigned omx = (unsigned)__shfl_xor((int)kmx, m, 64);
        kmn = (omn < kmn) ? omn : kmn;
        kmx = (omx < kmx) ? omx : kmx;
    }
    if ((tid & 63) == 0) {
        atomicMin(&mmx[0], kmn);
        atomicMin(&mmx[1], kmx);
    }
}

__global__ __launch_bounds__(256) void nerf_norm(float* __restrict__ out,
                                                 const unsigned int* __restrict__ mmx)
{
    int idx = blockIdx.x * 256 + threadIdx.x;
    float mn = __uint_as_float(mmx[0]);
    float mx = __uint_as_float(~mmx[1]);
    float v = out[786432 + idx];
    out[786432 + idx] = (v - mn) * __builtin_amdgcn_rcpf(mx - mn);
}

extern "C" void kernel_launch(void* const* d_in, const int* in_sizes, int n_in,
                              void* d_out, int out_size, void* d_ws, size_t ws_size,
                              hipStream_t stream) {
    (void)in_sizes; (void)n_in; (void)out_size; (void)ws_size;
    const float* tm = (const float*)d_in[0];
    const float* wq = (const float*)d_in[1];
    float* out = (float*)d_out;
    unsigned int* mmx = (unsigned int*)d_ws;
    hipMemsetAsync(d_ws, 0xFF, 8, stream);             // both min-keys -> UINT_MAX
    nerf_main<<<NRAYS/64, NT, 0, stream>>>(tm, wq, out, mmx);
    nerf_norm<<<NRAYS/256, 256, 0, stream>>>(out, mmx);
}

// Round 11
// 186.947 us; speedup vs baseline: 1.3740x; 1.3740x over previous
//
#include <hip/hip_runtime.h>
#include <math.h>

// R8 main kernel VERBATIM (85 us, twice-validated: 2 rays/thread scalar, branchless
// P2/P3, one-ahead LDS window) + ONLY change: fused min/max+normalize via
// counter-spin grid barrier. 1024 blocks x 33.3 KB LDS = exactly 4 blocks/CU
// co-resident (LDS 4x33.3<=160, VGPR 132<=512/SIMD at 1 wave/SIMD) -> spin is
// deadlock-free. R7/R9 confounded the spin with main-loop regressions; this
// round isolates it. If main >= 120 us: spin costs ~40 us -> revert to R8 split.

#define NT 64
#define PTS 64
#define NRAYS (2*256*256)
#define NBLK (NRAYS/128)          // 1024 blocks, 2 rays/thread
#define NEARV 0.1f
#define STEPV (1.9f/63.0f)
#define FAR63 (0.1f + 63.0f*(1.9f/63.0f))
#define NL2E (-1.4426950408889634f)

extern "C" __device__ float __ocml_native_exp2_f32(float);

__device__ __forceinline__ float sig_pm(float arg) {   // arg is already -x*log2e
    return __builtin_amdgcn_rcpf(1.0f + __ocml_native_exp2_f32(arg));
}

__global__ __launch_bounds__(NT) void nerf_main(
    const float* __restrict__ tm, const float* __restrict__ wq,
    float* __restrict__ out, unsigned int* __restrict__ cnt,
    float* __restrict__ part)
{
    __shared__ float fd[2][PTS + 1][NT];   // per-ray fine depths + junk pad row
    const int tid = threadIdx.x;
    int rr[2];
    rr[0] = blockIdx.x * 128 + tid;
    rr[1] = rr[0] + 64;

    float bA[2][4], sA[2][4];              // feat[c]*(-log2e) = bA + d*sA
    int bb_[2], nn_[2];
    #pragma unroll
    for (int q = 0; q < 2; q++) {
        int r = rr[q];
        int b = r >> 16, n = r & 65535;
        bb_[q] = b; nn_[q] = n;
        int i = n >> 8, j = n & 255;
        float cx = (1.0f + (float)j * (-2.0f/255.0f)) * (1.0f/4.2f);
        float cy = (1.0f + (float)i * (-2.0f/255.0f)) * (1.0f/4.2f);
        const float* tmb = tm + b*12;
        float dx = tmb[0]*cx + tmb[1]*cy + tmb[2];
        float dy = tmb[4]*cx + tmb[5]*cy + tmb[6];
        float dz = tmb[8]*cx + tmb[9]*cy + tmb[10];
        float ox = tmb[3], oy = tmb[7], oz = tmb[11];
        #pragma unroll
        for (int c = 0; c < 4; c++) {
            float s  = dx*wq[0*4+c] + dy*wq[1*4+c] + dz*wq[2*4+c];
            float bv = ox*wq[0*4+c] + oy*wq[1*4+c] + oz*wq[2*4+c]
                     + dx*wq[3*4+c] + dy*wq[4*4+c] + dz*wq[5*4+c];
            sA[q][c] = s * NL2E;
            bA[q][c] = bv * NL2E;
        }
    }

    // ---- phase 1: coarse march, 2 rays interleaved ----
    float T[2] = {1.0f, 1.0f}, S[2] = {0.0f, 0.0f};
    float a0[2] = {0.0f, 0.0f}, a1[2] = {0.0f, 0.0f}, a2[2] = {0.0f, 0.0f};
    #pragma unroll 4
    for (int p = 0; p < PTS; p++) {
        float d = fmaf((float)p, STEPV, NEARV);
        #pragma unroll
        for (int q = 0; q < 2; q++) {
            float op = sig_pm(bA[q][0] + d*sA[q][0]);
            float v0 = sig_pm(bA[q][1] + d*sA[q][1]);
            float v1 = sig_pm(bA[q][2] + d*sA[q][2]);
            float v2 = sig_pm(bA[q][3] + d*sA[q][3]);
            float w  = op * T[q];
            a0[q] = fmaf(w, v0, a0[q]);
            a1[q] = fmaf(w, v1, a1[q]);
            a2[q] = fmaf(w, v2, a2[q]);
            S[q] += w + 1e-5f;
            T[q] *= (1.0f - op);
        }
    }
    #pragma unroll
    for (int q = 0; q < 2; q++) {
        out[(bb_[q]*3+0)*65536 + nn_[q]] = a0[q];
        out[(bb_[q]*3+1)*65536 + nn_[q]] = a1[q];
        out[(bb_[q]*3+2)*65536 + nn_[q]] = a2[q];
    }

    // ---- phase 2: branchless sampling machines, interleaved ----
    float Sinv[2], T2[2], c_lo[2], c_hi[2], bin_prev[2];
    int ind[2], kk[2];
    #pragma unroll
    for (int q = 0; q < 2; q++) {
        Sinv[q] = __builtin_amdgcn_rcpf(S[q]);
        float op0 = sig_pm(bA[q][0] + NEARV*sA[q][0]);
        T2[q]   = 1.0f - op0;
        c_lo[q] = 0.0f;
        c_hi[q] = (op0 + 1e-5f) * Sinv[q];   // cdf[0]
        ind[q] = 0; kk[q] = 1;
        bin_prev[q] = NEARV;                 // bin_0 == NEAR always
    }
    #pragma unroll 1
    for (int it = 0; it < 2*PTS; it++) {
        #pragma unroll
        for (int q = 0; q < 2; q++) {
            float u = (float)kk[q] * 0.015625f;          // exact k/64
            bool adv = (ind[q] < PTS) && (c_hi[q] <= u); // searchsorted 'right'
            float dn  = fmaf((float)min(ind[q] + 1, 63), STEPV, NEARV);
            float opn = sig_pm(bA[q][0] + dn*sA[q][0]);
            float wn  = opn * T2[q];
            float d0  = fmaf((float)(ind[q] - 1), STEPV, NEARV);
            float den = c_hi[q] - c_lo[q];
            den = (den < 1e-8f) ? 1.0f : den;            // ref guard
            float t = (u - c_lo[q]) * __builtin_amdgcn_rcpf(den);
            t = fminf(fmaxf(t, 0.0f), 1.0f);
            float bin = fmaf(t, STEPV, d0);
            bin = (ind[q] <= 0)   ? NEARV : bin;
            bin = (ind[q] >= PTS) ? FAR63 : bin;
            float fdep = 0.5f * (bin_prev[q] + bin);
            int widx = adv ? PTS : min(kk[q] - 1, PTS);  // pad row on advance
            fd[q][widx][tid] = fdep;                     // unconditional ds_write
            float nc_hi = c_hi[q] + (wn + 1e-5f) * Sinv[q];
            float nT2   = T2[q] * (1.0f - opn);
            c_lo[q]     = adv ? c_hi[q] : c_lo[q];
            c_hi[q]     = adv ? nc_hi   : c_hi[q];
            T2[q]       = adv ? nT2     : T2[q];
            bin_prev[q] = adv ? bin_prev[q] : bin;
            ind[q] += adv ? 1 : 0;
            kk[q]  += adv ? 0 : 1;
        }
    }

    // ---- phase 3: branchless merge, 2 rays interleaved ----
    float T3[2] = {1.0f, 1.0f}, sw[2] = {0.0f, 0.0f};
    float f0[2] = {0.0f, 0.0f}, f1[2] = {0.0f, 0.0f}, f2[2] = {0.0f, 0.0f};
    float rd[2] = {0.0f, 0.0f};
    int pc[2] = {0, 0}, pf[2] = {0, 0};
    float dc[2] = {NEARV, NEARV};
    float cur[2], nxt[2];
    #pragma unroll
    for (int q = 0; q < 2; q++) { cur[q] = fd[q][0][tid]; nxt[q] = fd[q][1][tid]; }
    #pragma unroll 1
    for (int it = 0; it < 2*PTS; it++) {
        #pragma unroll
        for (int q = 0; q < 2; q++) {
            float dfv = (pf[q] < PTS) ? cur[q] : 3.0e38f;
            bool tc = (pc[q] < PTS) && (dc[q] <= dfv);   // ties -> coarse (stable)
            float d = tc ? dc[q] : dfv;
            pc[q] += tc ? 1 : 0;
            dc[q] = fmaf((float)pc[q], STEPV, NEARV);
            pf[q] += tc ? 0 : 1;
            cur[q] = tc ? cur[q] : nxt[q];
            nxt[q] = fd[q][min(pf[q] + 1, PTS)][tid];    // unconditional ds_read
            float op = sig_pm(bA[q][0] + d*sA[q][0]);
            float v0 = sig_pm(bA[q][1] + d*sA[q][1]);
            float v1 = sig_pm(bA[q][2] + d*sA[q][2]);
            float v2 = sig_pm(bA[q][3] + d*sA[q][3]);
            float w  = op * T3[q];
            f0[q] = fmaf(w, v0, f0[q]);
            f1[q] = fmaf(w, v1, f1[q]);
            f2[q] = fmaf(w, v2, f2[q]);
            sw[q] += w;
            rd[q] = fmaf(w, d, rd[q]);
            T3[q] *= (1.0f - op);
        }
    }

    float rdep[2];
    #pragma unroll
    for (int q = 0; q < 2; q++) {
        out[393216 + (bb_[q]*3+0)*65536 + nn_[q]] = f0[q];
        out[393216 + (bb_[q]*3+1)*65536 + nn_[q]] = f1[q];
        out[393216 + (bb_[q]*3+2)*65536 + nn_[q]] = f2[q];
        float fop = fminf(fmaxf(sw[q], 0.0f), 1.0f);
        rdep[q] = rd[q] + (1.0f - fop) * 2.0f;           // d_all.max() == 2.0 exactly
    }

    // ---- fused min/max + normalize (counter-spin; 1024 blocks all co-resident) ----
    float mn = fminf(rdep[0], rdep[1]);
    float mx = fmaxf(rdep[0], rdep[1]);
    #pragma unroll
    for (int m = 32; m >= 1; m >>= 1) {
        mn = fminf(mn, __shfl_xor(mn, m, 64));
        mx = fmaxf(mx, __shfl_xor(mx, m, 64));
    }
    if (tid == 0) {
        part[2*blockIdx.x]     = mn;
        part[2*blockIdx.x + 1] = mx;
        __hip_atomic_fetch_add(cnt, 1u, __ATOMIC_RELEASE, __HIP_MEMORY_SCOPE_AGENT);
        while (__hip_atomic_load(cnt, __ATOMIC_ACQUIRE, __HIP_MEMORY_SCOPE_AGENT) < NBLK)
            __builtin_amdgcn_s_sleep(2);
    }
    __syncthreads();                       // single wave: reconverge + LDS/mem order
    mn = 3.4e38f; mx = -3.4e38f;
    #pragma unroll 1
    for (int q = tid; q < NBLK; q += NT) { // 16 pairs/lane, L2-hit
        float pmn = __hip_atomic_load(&part[2*q],     __ATOMIC_RELAXED, __HIP_MEMORY_SCOPE_AGENT);
        float pmx = __hip_atomic_load(&part[2*q + 1], __ATOMIC_RELAXED, __HIP_MEMORY_SCOPE_AGENT);
        mn = fminf(mn, pmn);
        mx = fmaxf(mx, pmx);
    }
    #pragma unroll
    for (int m = 32; m >= 1; m >>= 1) {
        mn = fminf(mn, __shfl_xor(mn, m, 64));
        mx = fmaxf(mx, __shfl_xor(mx, m, 64));
    }
    float inv = __builtin_amdgcn_rcpf(mx - mn);
    out[786432 + rr[0]] = (rdep[0] - mn) * inv;
    out[786432 + rr[1]] = (rdep[1] - mn) * inv;
}

extern "C" void kernel_launch(void* const* d_in, const int* in_sizes, int n_in,
                              void* d_out, int out_size, void* d_ws, size_t ws_size,
                              hipStream_t stream) {
    (void)in_sizes; (void)n_in; (void)out_size; (void)ws_size;
    const float* tm = (const float*)d_in[0];
    const float* wq = (const float*)d_in[1];
    float* out = (float*)d_out;
    unsigned int* cnt = (unsigned int*)d_ws;
    float* part = (float*)((char*)d_ws + 128);   // keep off the counter's line
    hipMemsetAsync(d_ws, 0, 4, stream);          // zero the arrival counter
    nerf_main<<<NBLK, NT, 0, stream>>>(tm, wq, out, cnt, part);
}

// Round 12
// 137.320 us; speedup vs baseline: 1.8705x; 1.3614x over previous
//
#include <hip/hip_runtime.h>
#include <math.h>

// FINAL: R8 configuration verbatim (best measured: main 85.0 us, total 137.2 us,
// absmax 0.0039). Two rays per thread, branchless P2/P3, split norm kernel.
// Locked-in findings from R1-R11:
//  - streams/SIMD = rays/(64*1024) = 2, arrangement-invariant (R4/R7/R8 busy
//    ~94k cyc/SIMD identical); latency-bound, not pipe-bound.
//  - cross-thread decompositions all lose: 64-lane shuffles 3x issue (R3),
//    tpr=8/16-reg arrays spill (R5/R6), LDS search machinery +busy+conflicts (R10).
//  - fused min/max+norm via grid-barrier spin costs ~+48 us (R7/R9/R11) -> split.
//  - NR-rcp and v2f packing regress (R9): native v_rcp + scalar fp32 win.

#define NT 64
#define PTS 64
#define NRAYS (2*256*256)
#define NEARV 0.1f
#define STEPV (1.9f/63.0f)
#define FAR63 (0.1f + 63.0f*(1.9f/63.0f))
#define NL2E (-1.4426950408889634f)

extern "C" __device__ float __ocml_native_exp2_f32(float);

__device__ __forceinline__ float sig_pm(float arg) {   // arg is already -x*log2e
    return __builtin_amdgcn_rcpf(1.0f + __ocml_native_exp2_f32(arg));
}

__global__ __launch_bounds__(NT) void nerf_main(
    const float* __restrict__ tm, const float* __restrict__ wq,
    float* __restrict__ out, unsigned int* __restrict__ mmx)
{
    __shared__ float fd[2][PTS + 1][NT];   // per-ray fine depths + junk pad row
    const int tid = threadIdx.x;
    int rr[2];
    rr[0] = blockIdx.x * 128 + tid;
    rr[1] = rr[0] + 64;

    float bA[2][4], sA[2][4];              // feat[c]*(-log2e) = bA + d*sA
    int bb_[2], nn_[2];
    #pragma unroll
    for (int q = 0; q < 2; q++) {
        int r = rr[q];
        int b = r >> 16, n = r & 65535;
        bb_[q] = b; nn_[q] = n;
        int i = n >> 8, j = n & 255;
        float cx = (1.0f + (float)j * (-2.0f/255.0f)) * (1.0f/4.2f);
        float cy = (1.0f + (float)i * (-2.0f/255.0f)) * (1.0f/4.2f);
        const float* tmb = tm + b*12;
        float dx = tmb[0]*cx + tmb[1]*cy + tmb[2];
        float dy = tmb[4]*cx + tmb[5]*cy + tmb[6];
        float dz = tmb[8]*cx + tmb[9]*cy + tmb[10];
        float ox = tmb[3], oy = tmb[7], oz = tmb[11];
        #pragma unroll
        for (int c = 0; c < 4; c++) {
            float s  = dx*wq[0*4+c] + dy*wq[1*4+c] + dz*wq[2*4+c];
            float bv = ox*wq[0*4+c] + oy*wq[1*4+c] + oz*wq[2*4+c]
                     + dx*wq[3*4+c] + dy*wq[4*4+c] + dz*wq[5*4+c];
            sA[q][c] = s * NL2E;
            bA[q][c] = bv * NL2E;
        }
    }

    // ---- phase 1: coarse march, 2 rays interleaved ----
    float T[2] = {1.0f, 1.0f}, S[2] = {0.0f, 0.0f};
    float a0[2] = {0.0f, 0.0f}, a1[2] = {0.0f, 0.0f}, a2[2] = {0.0f, 0.0f};
    #pragma unroll 4
    for (int p = 0; p < PTS; p++) {
        float d = fmaf((float)p, STEPV, NEARV);
        #pragma unroll
        for (int q = 0; q < 2; q++) {
            float op = sig_pm(bA[q][0] + d*sA[q][0]);
            float v0 = sig_pm(bA[q][1] + d*sA[q][1]);
            float v1 = sig_pm(bA[q][2] + d*sA[q][2]);
            float v2 = sig_pm(bA[q][3] + d*sA[q][3]);
            float w  = op * T[q];
            a0[q] = fmaf(w, v0, a0[q]);
            a1[q] = fmaf(w, v1, a1[q]);
            a2[q] = fmaf(w, v2, a2[q]);
            S[q] += w + 1e-5f;
            T[q] *= (1.0f - op);
        }
    }
    #pragma unroll
    for (int q = 0; q < 2; q++) {
        out[(bb_[q]*3+0)*65536 + nn_[q]] = a0[q];
        out[(bb_[q]*3+1)*65536 + nn_[q]] = a1[q];
        out[(bb_[q]*3+2)*65536 + nn_[q]] = a2[q];
    }

    // ---- phase 2: branchless sampling machines, interleaved ----
    float Sinv[2], T2[2], c_lo[2], c_hi[2], bin_prev[2];
    int ind[2], kk[2];
    #pragma unroll
    for (int q = 0; q < 2; q++) {
        Sinv[q] = __builtin_amdgcn_rcpf(S[q]);
        float op0 = sig_pm(bA[q][0] + NEARV*sA[q][0]);
        T2[q]   = 1.0f - op0;
        c_lo[q] = 0.0f;
        c_hi[q] = (op0 + 1e-5f) * Sinv[q];   // cdf[0]
        ind[q] = 0; kk[q] = 1;
        bin_prev[q] = NEARV;                 // bin_0 == NEAR always
    }
    #pragma unroll 1
    for (int it = 0; it < 2*PTS; it++) {
        #pragma unroll
        for (int q = 0; q < 2; q++) {
            float u = (float)kk[q] * 0.015625f;          // exact k/64
            bool adv = (ind[q] < PTS) && (c_hi[q] <= u); // searchsorted 'right'
            float dn  = fmaf((float)min(ind[q] + 1, 63), STEPV, NEARV);
            float opn = sig_pm(bA[q][0] + dn*sA[q][0]);
            float wn  = opn * T2[q];
            float d0  = fmaf((float)(ind[q] - 1), STEPV, NEARV);
            float den = c_hi[q] - c_lo[q];
            den = (den < 1e-8f) ? 1.0f : den;            // ref guard
            float t = (u - c_lo[q]) * __builtin_amdgcn_rcpf(den);
            t = fminf(fmaxf(t, 0.0f), 1.0f);
            float bin = fmaf(t, STEPV, d0);
            bin = (ind[q] <= 0)   ? NEARV : bin;
            bin = (ind[q] >= PTS) ? FAR63 : bin;
            float fdep = 0.5f * (bin_prev[q] + bin);
            int widx = adv ? PTS : min(kk[q] - 1, PTS);  // pad row on advance
            fd[q][widx][tid] = fdep;                     // unconditional ds_write
            float nc_hi = c_hi[q] + (wn + 1e-5f) * Sinv[q];
            float nT2   = T2[q] * (1.0f - opn);
            c_lo[q]     = adv ? c_hi[q] : c_lo[q];
            c_hi[q]     = adv ? nc_hi   : c_hi[q];
            T2[q]       = adv ? nT2     : T2[q];
            bin_prev[q] = adv ? bin_prev[q] : bin;
            ind[q] += adv ? 1 : 0;
            kk[q]  += adv ? 0 : 1;
        }
    }

    // ---- phase 3: branchless merge, 2 rays interleaved ----
    float T3[2] = {1.0f, 1.0f}, sw[2] = {0.0f, 0.0f};
    float f0[2] = {0.0f, 0.0f}, f1[2] = {0.0f, 0.0f}, f2[2] = {0.0f, 0.0f};
    float rd[2] = {0.0f, 0.0f};
    int pc[2] = {0, 0}, pf[2] = {0, 0};
    float dc[2] = {NEARV, NEARV};
    float cur[2], nxt[2];
    #pragma unroll
    for (int q = 0; q < 2; q++) { cur[q] = fd[q][0][tid]; nxt[q] = fd[q][1][tid]; }
    #pragma unroll 1
    for (int it = 0; it < 2*PTS; it++) {
        #pragma unroll
        for (int q = 0; q < 2; q++) {
            float dfv = (pf[q] < PTS) ? cur[q] : 3.0e38f;
            bool tc = (pc[q] < PTS) && (dc[q] <= dfv);   // ties -> coarse (stable)
            float d = tc ? dc[q] : dfv;
            pc[q] += tc ? 1 : 0;
            dc[q] = fmaf((float)pc[q], STEPV, NEARV);
            pf[q] += tc ? 0 : 1;
            cur[q] = tc ? cur[q] : nxt[q];
            nxt[q] = fd[q][min(pf[q] + 1, PTS)][tid];    // unconditional ds_read
            float op = sig_pm(bA[q][0] + d*sA[q][0]);
            float v0 = sig_pm(bA[q][1] + d*sA[q][1]);
            float v1 = sig_pm(bA[q][2] + d*sA[q][2]);
            float v2 = sig_pm(bA[q][3] + d*sA[q][3]);
            float w  = op * T3[q];
            f0[q] = fmaf(w, v0, f0[q]);
            f1[q] = fmaf(w, v1, f1[q]);
            f2[q] = fmaf(w, v2, f2[q]);
            sw[q] += w;
            rd[q] = fmaf(w, d, rd[q]);
            T3[q] *= (1.0f - op);
        }
    }

    unsigned kmn = 0xFFFFFFFFu, kmx = 0xFFFFFFFFu;
    #pragma unroll
    for (int q = 0; q < 2; q++) {
        out[393216 + (bb_[q]*3+0)*65536 + nn_[q]] = f0[q];
        out[393216 + (bb_[q]*3+1)*65536 + nn_[q]] = f1[q];
        out[393216 + (bb_[q]*3+2)*65536 + nn_[q]] = f2[q];
        float fop  = fminf(fmaxf(sw[q], 0.0f), 1.0f);
        float rdep = rd[q] + (1.0f - fop) * 2.0f;        // d_all.max() == 2.0 exactly
        out[786432 + rr[q]] = rdep;
        unsigned ub = __float_as_uint(rdep);             // rdep>0: u32 order == float order
        kmn = min(kmn, ub);
        kmx = min(kmx, ~ub);
    }
    #pragma unroll
    for (int m = 32; m >= 1; m >>= 1) {
        unsigned omn = (unsigned)__shfl_xor((int)kmn, m, 64);
        unsigned omx = (unsigned)__shfl_xor((int)kmx, m, 64);
        kmn = (omn < kmn) ? omn : kmn;
        kmx = (omx < kmx) ? omx : kmx;
    }
    if (tid == 0) {
        atomicMin(&mmx[0], kmn);
        atomicMin(&mmx[1], kmx);
    }
}

__global__ __launch_bounds__(256) void nerf_norm(float* __restrict__ out,
                                                 const unsigned int* __restrict__ mmx)
{
    int idx = blockIdx.x * 256 + threadIdx.x;
    float mn = __uint_as_float(mmx[0]);
    float mx = __uint_as_float(~mmx[1]);
    float v = out[786432 + idx];
    out[786432 + idx] = (v - mn) * __builtin_amdgcn_rcpf(mx - mn);
}

extern "C" void kernel_launch(void* const* d_in, const int* in_sizes, int n_in,
                              void* d_out, int out_size, void* d_ws, size_t ws_size,
                              hipStream_t stream) {
    (void)in_sizes; (void)n_in; (void)out_size; (void)ws_size;
    const float* tm = (const float*)d_in[0];
    const float* wq = (const float*)d_in[1];
    float* out = (float*)d_out;
    unsigned int* mmx = (unsigned int*)d_ws;
    hipMemsetAsync(d_ws, 0xFF, 8, stream);     // both min-keys -> UINT_MAX
    nerf_main<<<NRAYS/128, NT, 0, stream>>>(tm, wq, out, mmx);
    nerf_norm<<<NRAYS/256, 256, 0, stream>>>(out, mmx);
}